// Round 1
// 226.720 us; speedup vs baseline: 1.0084x; 1.0084x over previous
//
#include <hip/hip_runtime.h>
#include <hip/hip_bf16.h>

#define NN 100000
#define NE 1600000

typedef __bf16 bf16x8 __attribute__((ext_vector_type(8)));
typedef float  f32x4  __attribute__((ext_vector_type(4)));

__device__ inline int rfl(int x) { return __builtin_amdgcn_readfirstlane(x); }

__device__ inline void acc2(float& a, float& b, unsigned int u) {
    a += __uint_as_float(u << 16);
    b += __uint_as_float(u & 0xffff0000u);
}

__device__ inline unsigned int pack_bf2(float x, float y) {
    union { __hip_bfloat162 h; unsigned int u; } p;
    p.h = __float22bfloat162_rn(make_float2(x, y));
    return p.u;
}

// ---------------------------------------------------------------------------
// Fused prep: blocks [0,6250) build CSR row_ptr from sorted edge_row;
// blocks [6250,6346) pack W0/W1 to bf16 [n][k] (B-operand layout).
// ---------------------------------------------------------------------------
__global__ __launch_bounds__(256) void prep_kernel(const int* __restrict__ row,
                                                   int* __restrict__ row_ptr,
                                                   const float* __restrict__ W0,
                                                   const float* __restrict__ W1,
                                                   __hip_bfloat16* __restrict__ Wt0,
                                                   __hip_bfloat16* __restrict__ Wt1) {
    int b = blockIdx.x;
    if (b < NE / 256) {
        int e = b * 256 + threadIdx.x;
        int r  = row[e];
        int rp = (e == 0) ? -1 : row[e - 1];
        for (int i = rp + 1; i <= r; ++i) row_ptr[i] = e;
        if (e == NE - 1) {
            for (int i = r + 1; i <= NN; ++i) row_ptr[i] = NE;
        }
    } else {
        int idx = (b - NE / 256) * 256 + threadIdx.x;
        if (idx < 128 * 128) {
            int n = idx >> 7, k = idx & 127;
            Wt0[idx] = __float2bfloat16(W0[(size_t)k * 128 + n]);
        } else {
            int r2 = idx - 128 * 128;          // < 64*128 by grid size
            int n = r2 >> 7, k = r2 & 127;
            Wt1[r2] = __float2bfloat16(W1[(size_t)k * 64 + n]);
        }
    }
}

__device__ inline float deg_scale(const int* __restrict__ row_ptr, int i) {
    int dg = row_ptr[i + 1] - row_ptr[i];
    return (dg > 0) ? rsqrtf((float)dg) : 0.0f;
}

// ---------------------------------------------------------------------------
// MFMA bf16 GEMM (layer 0): out[M,128] = dinv[r]*(X[M,128] @ Wt^T + bias).
// (unchanged from previous round)
// ---------------------------------------------------------------------------
template <int NO, typename InT>
__global__ __launch_bounds__(512) void gemm_mfma(const InT* __restrict__ X,
                                                 const __hip_bfloat16* __restrict__ Wt,
                                                 const float* __restrict__ bias,
                                                 const int* __restrict__ row_ptr,
                                                 __hip_bfloat16* __restrict__ out, int M) {
    constexpr int NT = NO / 16;
    __shared__ unsigned short SH[128 * 128];   // Ws role, then Cs role

    const int t = threadIdx.x;
    const int w = t >> 6, lane = t & 63;
    const int l15 = lane & 15, quad = lane >> 4;
    const int rbase = blockIdx.x * 128;

    for (int i = t; i < NO * 16; i += 512) {
        int n = i >> 4, g = i & 15;
        *(uint4*)&SH[n * 128 + ((g ^ (n & 7)) << 3)] = ((const uint4*)Wt)[i];
    }
    __syncthreads();

    const int arow_g = rbase + w * 16 + l15;
    const int arow   = (arow_g < M) ? arow_g : (M - 1);

    bf16x8 af[4];
    if constexpr (sizeof(InT) == 4) {
        float4 lo[4], hi[4];
#pragma unroll
        for (int kc = 0; kc < 4; ++kc) {
            const float4* src = (const float4*)&X[(size_t)arow * 128 + kc * 32 + quad * 8];
            lo[kc] = src[0];
            hi[kc] = src[1];
        }
#pragma unroll
        for (int kc = 0; kc < 4; ++kc) {
            union { bf16x8 v; __hip_bfloat162 h[4]; } u;
            u.h[0] = __float22bfloat162_rn(make_float2(lo[kc].x, lo[kc].y));
            u.h[1] = __float22bfloat162_rn(make_float2(lo[kc].z, lo[kc].w));
            u.h[2] = __float22bfloat162_rn(make_float2(hi[kc].x, hi[kc].y));
            u.h[3] = __float22bfloat162_rn(make_float2(hi[kc].z, hi[kc].w));
            af[kc] = u.v;
        }
    } else {
        union { bf16x8 v; uint4 q; } u[4];
#pragma unroll
        for (int kc = 0; kc < 4; ++kc)
            u[kc].q = *(const uint4*)&X[(size_t)arow * 128 + kc * 32 + quad * 8];
#pragma unroll
        for (int kc = 0; kc < 4; ++kc) af[kc] = u[kc].v;
    }

    f32x4 acc[NT];
#pragma unroll
    for (int nt = 0; nt < NT; ++nt) {
        float bv = bias[nt * 16 + l15];
        acc[nt][0] = bv; acc[nt][1] = bv; acc[nt][2] = bv; acc[nt][3] = bv;
    }

#pragma unroll
    for (int kc = 0; kc < 4; ++kc) {
#pragma unroll
        for (int nt = 0; nt < NT; ++nt) {
            int brow = nt * 16 + l15;
            bf16x8 bfr = *(const bf16x8*)&SH[brow * 128 + (((kc * 4 + quad) ^ (brow & 7)) << 3)];
            acc[nt] = __builtin_amdgcn_mfma_f32_16x16x32_bf16(af[kc], bfr, acc[nt], 0, 0, 0);
        }
    }
    __syncthreads();   // all waves done reading Ws before SH becomes Cs

    __hip_bfloat16* Cp = (__hip_bfloat16*)SH;
#pragma unroll
    for (int r4 = 0; r4 < 4; ++r4) {
        int lrow = w * 16 + quad * 4 + r4;
        int grow = rbase + lrow;
        float sc = (grow < M) ? deg_scale(row_ptr, grow) : 0.f;
#pragma unroll
        for (int nt = 0; nt < NT; ++nt) {
            int ct = nt * 16 + l15;
            Cp[lrow * 128 + ((((ct >> 3) ^ (lrow & 7)) << 3)) + (ct & 7)] =
                __float2bfloat16(acc[nt][r4] * sc);
        }
    }
    constexpr int RJ  = NO / 8;
    constexpr int CNT = (16 * RJ) / 64;
#pragma unroll
    for (int k = 0; k < CNT; ++k) {
        int idx = k * 64 + lane;
        int lr16 = idx / RJ, j = idx % RJ;
        int lrow = w * 16 + lr16;
        int grow = rbase + lrow;
        if (grow < M) {
            uint4 v = *(const uint4*)&Cp[lrow * 128 + ((j ^ (lrow & 7)) << 3)];
            *(uint4*)&out[(size_t)grow * NO + (j << 3)] = v;
        }
    }
}

// ---------------------------------------------------------------------------
// FUSED SpMM+ReLU+GEMM1. Phase 1 REWRITTEN: uniform software-pipelined
// ping-pong of two 16-edge batches (32 edges / 8 gathers in flight per wave).
// All degrees take the same pipelined path (clamped issue + zero-masked
// consume) — the previous fully-serial 4-edge tail (hit by ~47% of rows,
// deg<16) is gone. Phase 2 (32x64 MFMA vs Wt1 in LDS) unchanged.
// ---------------------------------------------------------------------------
__global__ __launch_bounds__(512) void spmm_relu_gemm1(const int* __restrict__ row_ptr,
                                                       const int* __restrict__ col,
                                                       const uint4* __restrict__ H4, // h0b rows = 16 uint4
                                                       const __hip_bfloat16* __restrict__ Wt1,
                                                       const float* __restrict__ b1,
                                                       __hip_bfloat16* __restrict__ out) {
    __shared__ unsigned short As[32 * 128];   // h1 tile (bf16, swizzled)
    __shared__ unsigned short Ws[64 * 128];   // Wt1 (bf16, swizzled)

    const int t = threadIdx.x;
    const int w = t >> 6, lane = t & 63;
    const int l15 = lane & 15, quad = lane >> 4;
    const int rbase = blockIdx.x * 32;
    const int p = lane >> 4;                  // edge slot 0..3
    const int q = lane & 15;                  // feature granule (8 features)

    // stage Wt1 (64 x 128) -> Ws, swizzled
    for (int i = t; i < 64 * 16; i += 512) {
        int n = i >> 4, g = i & 15;
        *(uint4*)&Ws[n * 128 + ((g ^ (n & 7)) << 3)] = ((const uint4*)Wt1)[i];
    }

    // ---- phase 1: gather 4 rows per wave into As, pipelined batches
#pragma unroll 1
    for (int rr = 0; rr < 4; ++rr) {
        const int il = w * 4 + rr;
        const int i  = rbase + il;
        const int e0 = rfl(row_ptr[i]);
        const int e1 = rfl(row_ptr[i + 1]);
        const int dg = e1 - e0;
        const float di = (dg > 0) ? rsqrtf((float)dg) : 0.0f;
        float a0 = 0.f, a1 = 0.f, a2 = 0.f, a3 = 0.f,
              a4 = 0.f, a5 = 0.f, a6 = 0.f, a7 = 0.f;

        if (dg > 0) {
            const int em = e1 - 1;
            uint4 va[4], vb[4];

            // issue one 16-edge batch (4 gather instrs, 4 edges each)
            auto ISSUE = [&](uint4* v, int base, bool full) {
#pragma unroll
                for (int g2 = 0; g2 < 4; ++g2) {
                    int eb = base + g2 * 4;
                    int j0 = eb, j1 = eb + 1, j2 = eb + 2, j3 = eb + 3;
                    if (!full) {
                        j0 = (j0 > em) ? em : j0;
                        j1 = (j1 > em) ? em : j1;
                        j2 = (j2 > em) ? em : j2;
                        j3 = (j3 > em) ? em : j3;
                    }
                    int s0 = rfl(col[j0]), s1 = rfl(col[j1]);
                    int s2 = rfl(col[j2]), s3 = rfl(col[j3]);
                    int c01 = (p & 1) ? s1 : s0;
                    int c23 = (p & 1) ? s3 : s2;
                    int c   = (p & 2) ? c23 : c01;
                    v[g2] = H4[(size_t)c * 16 + q];
                }
            };
            // consume one batch (zero-mask out-of-range lanes when !full)
            auto CONSUME = [&](const uint4* v, int base, bool full) {
#pragma unroll
                for (int g2 = 0; g2 < 4; ++g2) {
                    uint4 u = v[g2];
                    if (!full && (base + g2 * 4 + p >= e1)) {
                        u.x = 0u; u.y = 0u; u.z = 0u; u.w = 0u;
                    }
                    acc2(a0, a1, u.x); acc2(a2, a3, u.y);
                    acc2(a4, a5, u.z); acc2(a6, a7, u.w);
                }
            };

            const int  nb = (dg + 15) >> 4;        // #16-edge batches (>=1)
            const bool lastfull = (dg & 15) == 0;  // last batch exactly full?

            ISSUE(va, e0, nb > 1 || lastfull);
            int b = 1;
#pragma unroll 1
            for (; b + 1 < nb; b += 2) {           // steady state: 2 batches in flight
                ISSUE(vb, e0 + 16 * b, true);
                CONSUME(va, e0 + 16 * (b - 1), true);
                ISSUE(va, e0 + 16 * (b + 1), (b + 1 < nb - 1) || lastfull);
                CONSUME(vb, e0 + 16 * b, true);
            }
            if (b < nb) {                          // one trailing batch (b == nb-1)
                ISSUE(vb, e0 + 16 * b, lastfull);
                CONSUME(va, e0 + 16 * (b - 1), true);
                CONSUME(vb, e0 + 16 * b, lastfull);
            } else {                               // single-batch row drained here
                CONSUME(va, e0 + 16 * (b - 1), (b - 1 < nb - 1) || lastfull);
            }
        }

        // sum the 4 edge slots
#pragma unroll
        for (int off = 16; off < 64; off <<= 1) {
            a0 += __shfl_xor(a0, off, 64); a1 += __shfl_xor(a1, off, 64);
            a2 += __shfl_xor(a2, off, 64); a3 += __shfl_xor(a3, off, 64);
            a4 += __shfl_xor(a4, off, 64); a5 += __shfl_xor(a5, off, 64);
            a6 += __shfl_xor(a6, off, 64); a7 += __shfl_xor(a7, off, 64);
        }
        if (p == 0) {
            uint4 pk;
            pk.x = pack_bf2(fmaxf(a0 * di, 0.f), fmaxf(a1 * di, 0.f));
            pk.y = pack_bf2(fmaxf(a2 * di, 0.f), fmaxf(a3 * di, 0.f));
            pk.z = pack_bf2(fmaxf(a4 * di, 0.f), fmaxf(a5 * di, 0.f));
            pk.w = pack_bf2(fmaxf(a6 * di, 0.f), fmaxf(a7 * di, 0.f));
            *(uint4*)&As[il * 128 + ((q ^ (il & 7)) << 3)] = pk;
        }
    }
    __syncthreads();

    // ---- phase 2: 32x64 = As(32x128) @ Ws^T
    const int rb = (w & 1) * 16;
    const int cb = (w >> 1) * 16;
    const int arow_l = rb + l15;
    const int asw = arow_l & 7;

    f32x4 acc;
    {
        float bv = b1[cb + l15];
        acc[0] = bv; acc[1] = bv; acc[2] = bv; acc[3] = bv;
    }
#pragma unroll
    for (int kc = 0; kc < 4; ++kc) {
        bf16x8 af = *(const bf16x8*)&As[arow_l * 128 + (((kc * 4 + quad) ^ asw) << 3)];
        int brow = cb + l15;
        bf16x8 bfr = *(const bf16x8*)&Ws[brow * 128 + (((kc * 4 + quad) ^ (brow & 7)) << 3)];
        acc = __builtin_amdgcn_mfma_f32_16x16x32_bf16(af, bfr, acc, 0, 0, 0);
    }

#pragma unroll
    for (int r4 = 0; r4 < 4; ++r4) {
        int grow = rbase + rb + quad * 4 + r4;
        float sc = deg_scale(row_ptr, grow);
        out[(size_t)grow * 64 + cb + l15] = __float2bfloat16(acc[r4] * sc);
    }
}

// ---------------------------------------------------------------------------
// SpMM (CSR, wave-per-row), F=64, fused log_softmax. REWRITTEN gather:
// ping-pong of two 8-edge batches (2 gathers / 16 edges in flight) — the
// typical row (deg~16 -> 2 batches) now overlaps both gathers instead of
// running two serial load->wait->acc chains.
// ---------------------------------------------------------------------------
__global__ __launch_bounds__(256) void spmm_logsoftmax_64(const int* __restrict__ row_ptr,
                                                          const int* __restrict__ col,
                                                          const uint4* __restrict__ H4, // h2b rows = 8 uint4
                                                          float* __restrict__ out, int N) {
    const int lane = threadIdx.x & 63;
    const int p = lane >> 3;                  // edge slot 0..7
    const int q = lane & 7;                   // feature granule (8 features)
    int i = rfl(blockIdx.x * 4 + (threadIdx.x >> 6));
    if (i >= N) return;
    const int e0 = rfl(row_ptr[i]);
    const int e1 = rfl(row_ptr[i + 1]);
    const int dg = e1 - e0;
    const float di = (dg > 0) ? rsqrtf((float)dg) : 0.0f;
    float a0 = 0.f, a1 = 0.f, a2 = 0.f, a3 = 0.f,
          a4 = 0.f, a5 = 0.f, a6 = 0.f, a7 = 0.f;

    if (dg > 0) {
        const int em = e1 - 1;
        uint4 ua, ub;

        auto ISSUE = [&](uint4& u, int base, bool full) {
            int j0 = base,     j1 = base + 1, j2 = base + 2, j3 = base + 3;
            int j4 = base + 4, j5 = base + 5, j6 = base + 6, j7 = base + 7;
            if (!full) {
                j0 = (j0 > em) ? em : j0; j1 = (j1 > em) ? em : j1;
                j2 = (j2 > em) ? em : j2; j3 = (j3 > em) ? em : j3;
                j4 = (j4 > em) ? em : j4; j5 = (j5 > em) ? em : j5;
                j6 = (j6 > em) ? em : j6; j7 = (j7 > em) ? em : j7;
            }
            int s0 = rfl(col[j0]), s1 = rfl(col[j1]);
            int s2 = rfl(col[j2]), s3 = rfl(col[j3]);
            int s4 = rfl(col[j4]), s5 = rfl(col[j5]);
            int s6 = rfl(col[j6]), s7 = rfl(col[j7]);
            int b0 = (p & 1) ? s1 : s0, b1_ = (p & 1) ? s3 : s2;
            int b2 = (p & 1) ? s5 : s4, b3_ = (p & 1) ? s7 : s6;
            int c0 = (p & 2) ? b1_ : b0, c1 = (p & 2) ? b3_ : b2;
            int c  = (p & 4) ? c1 : c0;
            u = H4[(size_t)c * 8 + q];
        };
        auto CONSUME = [&](uint4 u, int base, bool full) {
            if (!full && (base + p >= e1)) { u.x = 0u; u.y = 0u; u.z = 0u; u.w = 0u; }
            acc2(a0, a1, u.x); acc2(a2, a3, u.y);
            acc2(a4, a5, u.z); acc2(a6, a7, u.w);
        };

        const int  ng = (dg + 7) >> 3;        // #8-edge batches (>=1)
        const bool lastfull = (dg & 7) == 0;

        ISSUE(ua, e0, ng > 1 || lastfull);
        int g = 1;
#pragma unroll 1
        for (; g + 1 < ng; g += 2) {
            ISSUE(ub, e0 + 8 * g, true);
            CONSUME(ua, e0 + 8 * (g - 1), true);
            ISSUE(ua, e0 + 8 * (g + 1), (g + 1 < ng - 1) || lastfull);
            CONSUME(ub, e0 + 8 * g, true);
        }
        if (g < ng) {
            ISSUE(ub, e0 + 8 * g, lastfull);
            CONSUME(ua, e0 + 8 * (g - 1), true);
            CONSUME(ub, e0 + 8 * g, lastfull);
        } else {
            CONSUME(ua, e0 + 8 * (g - 1), (g - 1 < ng - 1) || lastfull);
        }
    }

    // sum the 8 edge slots
#pragma unroll
    for (int off = 8; off < 64; off <<= 1) {
        a0 += __shfl_xor(a0, off, 64); a1 += __shfl_xor(a1, off, 64);
        a2 += __shfl_xor(a2, off, 64); a3 += __shfl_xor(a3, off, 64);
        a4 += __shfl_xor(a4, off, 64); a5 += __shfl_xor(a5, off, 64);
        a6 += __shfl_xor(a6, off, 64); a7 += __shfl_xor(a7, off, 64);
    }
    a0 *= di; a1 *= di; a2 *= di; a3 *= di;
    a4 *= di; a5 *= di; a6 *= di; a7 *= di;
    // log_softmax over 64 features (8 per lane x 8 granules)
    float m = fmaxf(fmaxf(fmaxf(a0, a1), fmaxf(a2, a3)),
                    fmaxf(fmaxf(a4, a5), fmaxf(a6, a7)));
#pragma unroll
    for (int off = 1; off < 8; off <<= 1)
        m = fmaxf(m, __shfl_xor(m, off, 64));
    float s = __expf(a0 - m) + __expf(a1 - m) + __expf(a2 - m) + __expf(a3 - m)
            + __expf(a4 - m) + __expf(a5 - m) + __expf(a6 - m) + __expf(a7 - m);
#pragma unroll
    for (int off = 1; off < 8; off <<= 1)
        s += __shfl_xor(s, off, 64);
    float ls = __logf(s);
    if (p == 0) {
        float4 o0 = make_float4(a0 - m - ls, a1 - m - ls, a2 - m - ls, a3 - m - ls);
        float4 o1 = make_float4(a4 - m - ls, a5 - m - ls, a6 - m - ls, a7 - m - ls);
        *(float4*)&out[(size_t)i * 64 + q * 8]     = o0;
        *(float4*)&out[(size_t)i * 64 + q * 8 + 4] = o1;
    }
}

// ---------------------------------------------------------------------------
extern "C" void kernel_launch(void* const* d_in, const int* in_sizes, int n_in,
                              void* d_out, int out_size, void* d_ws, size_t ws_size,
                              hipStream_t stream) {
    const float* x    = (const float*)d_in[0];
    const int*   erow = (const int*)d_in[1];
    const int*   ecol = (const int*)d_in[2];
    const float* W0   = (const float*)d_in[3];
    const float* b0   = (const float*)d_in[4];
    const float* W1   = (const float*)d_in[5];
    const float* b1   = (const float*)d_in[6];
    float* out = (float*)d_out;

    char* ws = (char*)d_ws;
    // layout (bytes):
    //   [0, 512K)            row_ptr (100001 int)
    //   [1M, +25.6M)         h0b  bf16 100000*128   (pre-scaled by dinv[row])
    //   [27M, +12.8M)        h2b  bf16 100000*64    (pre-scaled by dinv[row])
    //   [41M, +32K)          Wt0  bf16 128*128 (as [n][k])
    //   [41.1M, +16K)        Wt1  bf16 64*128  (as [n][k])
    int*             row_ptr = (int*)ws;
    __hip_bfloat16*  h0b     = (__hip_bfloat16*)(ws + (1u << 20));
    __hip_bfloat16*  h2b     = (__hip_bfloat16*)(ws + 27000000u);
    __hip_bfloat16*  Wt0     = (__hip_bfloat16*)(ws + 41000000u);
    __hip_bfloat16*  Wt1     = (__hip_bfloat16*)(ws + 41100000u);

    // 1. prep: row_ptr + packed weights
    prep_kernel<<<NE / 256 + 96, 256, 0, stream>>>(erow, row_ptr, W0, W1, Wt0, Wt1);
    // 2. h0b = bf16(dinv[r] * (x @ W0 + b0))        [MFMA, shared-LDS]
    gemm_mfma<128, float><<<(NN + 127) / 128, 512, 0, stream>>>(x, Wt0, b0, row_ptr, h0b, NN);
    // 3. h2b = bf16(dinv[r] * (relu(spmm(h0b)) @ W1 + b1))   [pipelined gathers]
    spmm_relu_gemm1<<<NN / 32, 512, 0, stream>>>(row_ptr, ecol,
                                                 (const uint4*)h0b, Wt1, b1, h2b);
    // 4. out = log_softmax(di * sum H[col])                  [pipelined gathers]
    spmm_logsoftmax_64<<<(NN + 3) / 4, 256, 0, stream>>>(row_ptr, ecol,
                                                         (const uint4*)h2b, out, NN);
}

// Round 2
// 225.437 us; speedup vs baseline: 1.0141x; 1.0057x over previous
//
#include <hip/hip_runtime.h>
#include <hip/hip_bf16.h>

#define NN 100000
#define NE 1600000

typedef __bf16 bf16x8 __attribute__((ext_vector_type(8)));
typedef float  f32x4  __attribute__((ext_vector_type(4)));

__device__ inline int rfl(int x) { return __builtin_amdgcn_readfirstlane(x); }

__device__ inline void acc2(float& a, float& b, unsigned int u) {
    a += __uint_as_float(u << 16);
    b += __uint_as_float(u & 0xffff0000u);
}

__device__ inline unsigned int pack_bf2(float x, float y) {
    union { __hip_bfloat162 h; unsigned int u; } p;
    p.h = __float22bfloat162_rn(make_float2(x, y));
    return p.u;
}

// ---------------------------------------------------------------------------
// Fused prep: blocks [0,6250) build CSR row_ptr from sorted edge_row;
// blocks [6250,6346) pack W0/W1 to bf16 [n][k] (B-operand layout).
// ---------------------------------------------------------------------------
__global__ __launch_bounds__(256) void prep_kernel(const int* __restrict__ row,
                                                   int* __restrict__ row_ptr,
                                                   const float* __restrict__ W0,
                                                   const float* __restrict__ W1,
                                                   __hip_bfloat16* __restrict__ Wt0,
                                                   __hip_bfloat16* __restrict__ Wt1) {
    int b = blockIdx.x;
    if (b < NE / 256) {
        int e = b * 256 + threadIdx.x;
        int r  = row[e];
        int rp = (e == 0) ? -1 : row[e - 1];
        for (int i = rp + 1; i <= r; ++i) row_ptr[i] = e;
        if (e == NE - 1) {
            for (int i = r + 1; i <= NN; ++i) row_ptr[i] = NE;
        }
    } else {
        int idx = (b - NE / 256) * 256 + threadIdx.x;
        if (idx < 128 * 128) {
            int n = idx >> 7, k = idx & 127;
            Wt0[idx] = __float2bfloat16(W0[(size_t)k * 128 + n]);
        } else {
            int r2 = idx - 128 * 128;          // < 64*128 by grid size
            int n = r2 >> 7, k = r2 & 127;
            Wt1[r2] = __float2bfloat16(W1[(size_t)k * 64 + n]);
        }
    }
}

__device__ inline float deg_scale(const int* __restrict__ row_ptr, int i) {
    int dg = row_ptr[i + 1] - row_ptr[i];
    return (dg > 0) ? rsqrtf((float)dg) : 0.0f;
}

// ---------------------------------------------------------------------------
// MFMA bf16 GEMM (layer 0): out[M,128] = dinv[r]*(X[M,128] @ Wt^T + bias).
// (unchanged)
// ---------------------------------------------------------------------------
template <int NO, typename InT>
__global__ __launch_bounds__(512) void gemm_mfma(const InT* __restrict__ X,
                                                 const __hip_bfloat16* __restrict__ Wt,
                                                 const float* __restrict__ bias,
                                                 const int* __restrict__ row_ptr,
                                                 __hip_bfloat16* __restrict__ out, int M) {
    constexpr int NT = NO / 16;
    __shared__ unsigned short SH[128 * 128];   // Ws role, then Cs role

    const int t = threadIdx.x;
    const int w = t >> 6, lane = t & 63;
    const int l15 = lane & 15, quad = lane >> 4;
    const int rbase = blockIdx.x * 128;

    for (int i = t; i < NO * 16; i += 512) {
        int n = i >> 4, g = i & 15;
        *(uint4*)&SH[n * 128 + ((g ^ (n & 7)) << 3)] = ((const uint4*)Wt)[i];
    }
    __syncthreads();

    const int arow_g = rbase + w * 16 + l15;
    const int arow   = (arow_g < M) ? arow_g : (M - 1);

    bf16x8 af[4];
    if constexpr (sizeof(InT) == 4) {
        float4 lo[4], hi[4];
#pragma unroll
        for (int kc = 0; kc < 4; ++kc) {
            const float4* src = (const float4*)&X[(size_t)arow * 128 + kc * 32 + quad * 8];
            lo[kc] = src[0];
            hi[kc] = src[1];
        }
#pragma unroll
        for (int kc = 0; kc < 4; ++kc) {
            union { bf16x8 v; __hip_bfloat162 h[4]; } u;
            u.h[0] = __float22bfloat162_rn(make_float2(lo[kc].x, lo[kc].y));
            u.h[1] = __float22bfloat162_rn(make_float2(lo[kc].z, lo[kc].w));
            u.h[2] = __float22bfloat162_rn(make_float2(hi[kc].x, hi[kc].y));
            u.h[3] = __float22bfloat162_rn(make_float2(hi[kc].z, hi[kc].w));
            af[kc] = u.v;
        }
    } else {
        union { bf16x8 v; uint4 q; } u[4];
#pragma unroll
        for (int kc = 0; kc < 4; ++kc)
            u[kc].q = *(const uint4*)&X[(size_t)arow * 128 + kc * 32 + quad * 8];
#pragma unroll
        for (int kc = 0; kc < 4; ++kc) af[kc] = u[kc].v;
    }

    f32x4 acc[NT];
#pragma unroll
    for (int nt = 0; nt < NT; ++nt) {
        float bv = bias[nt * 16 + l15];
        acc[nt][0] = bv; acc[nt][1] = bv; acc[nt][2] = bv; acc[nt][3] = bv;
    }

#pragma unroll
    for (int kc = 0; kc < 4; ++kc) {
#pragma unroll
        for (int nt = 0; nt < NT; ++nt) {
            int brow = nt * 16 + l15;
            bf16x8 bfr = *(const bf16x8*)&SH[brow * 128 + (((kc * 4 + quad) ^ (brow & 7)) << 3)];
            acc[nt] = __builtin_amdgcn_mfma_f32_16x16x32_bf16(af[kc], bfr, acc[nt], 0, 0, 0);
        }
    }
    __syncthreads();   // all waves done reading Ws before SH becomes Cs

    __hip_bfloat16* Cp = (__hip_bfloat16*)SH;
#pragma unroll
    for (int r4 = 0; r4 < 4; ++r4) {
        int lrow = w * 16 + quad * 4 + r4;
        int grow = rbase + lrow;
        float sc = (grow < M) ? deg_scale(row_ptr, grow) : 0.f;
#pragma unroll
        for (int nt = 0; nt < NT; ++nt) {
            int ct = nt * 16 + l15;
            Cp[lrow * 128 + ((((ct >> 3) ^ (lrow & 7)) << 3)) + (ct & 7)] =
                __float2bfloat16(acc[nt][r4] * sc);
        }
    }
    constexpr int RJ  = NO / 8;
    constexpr int CNT = (16 * RJ) / 64;
#pragma unroll
    for (int k = 0; k < CNT; ++k) {
        int idx = k * 64 + lane;
        int lr16 = idx / RJ, j = idx % RJ;
        int lrow = w * 16 + lr16;
        int grow = rbase + lrow;
        if (grow < M) {
            uint4 v = *(const uint4*)&Cp[lrow * 128 + ((j ^ (lrow & 7)) << 3)];
            *(uint4*)&out[(size_t)grow * NO + (j << 3)] = v;
        }
    }
}

// ---------------------------------------------------------------------------
// FUSED SpMM+ReLU+GEMM1. Phase 1: ping-pong of FULL 16-edge batches (no
// clamps/masks on the main path) + exactly ONE clamped tail batch, issued
// before the last full batch is consumed so its latency overlaps. Rows with
// deg<16 get a single 4-gathers-in-flight clamped batch (was serial).
// Phase 2 (32x64 MFMA vs Wt1 in LDS) unchanged.
// ---------------------------------------------------------------------------
__global__ __launch_bounds__(512) void spmm_relu_gemm1(const int* __restrict__ row_ptr,
                                                       const int* __restrict__ col,
                                                       const uint4* __restrict__ H4, // h0b rows = 16 uint4
                                                       const __hip_bfloat16* __restrict__ Wt1,
                                                       const float* __restrict__ b1,
                                                       __hip_bfloat16* __restrict__ out) {
    __shared__ unsigned short As[32 * 128];   // h1 tile (bf16, swizzled)
    __shared__ unsigned short Ws[64 * 128];   // Wt1 (bf16, swizzled)

    const int t = threadIdx.x;
    const int w = t >> 6, lane = t & 63;
    const int l15 = lane & 15, quad = lane >> 4;
    const int rbase = blockIdx.x * 32;
    const int p = lane >> 4;                  // edge slot 0..3
    const int q = lane & 15;                  // feature granule (8 features)

    // stage Wt1 (64 x 128) -> Ws, swizzled
    for (int i = t; i < 64 * 16; i += 512) {
        int n = i >> 4, g = i & 15;
        *(uint4*)&Ws[n * 128 + ((g ^ (n & 7)) << 3)] = ((const uint4*)Wt1)[i];
    }

    // ---- phase 1: gather 4 rows per wave into As
#pragma unroll 1
    for (int rr = 0; rr < 4; ++rr) {
        const int il = w * 4 + rr;
        const int i  = rbase + il;
        const int e0 = rfl(row_ptr[i]);
        const int e1 = rfl(row_ptr[i + 1]);
        const int dg = e1 - e0;
        const float di = (dg > 0) ? rsqrtf((float)dg) : 0.0f;
        float a0 = 0.f, a1 = 0.f, a2 = 0.f, a3 = 0.f,
              a4 = 0.f, a5 = 0.f, a6 = 0.f, a7 = 0.f;

        if (dg > 0) {
            const int em    = e1 - 1;
            const int nfull = dg >> 4;             // # full 16-edge batches
            const int tb    = e0 + (nfull << 4);   // tail base
            const bool tail = (dg & 15) != 0;
            uint4 va[4], vb[4];

            // full batch: no clamps, no masks
            auto ISSUEF = [&](uint4* v, int base) {
#pragma unroll
                for (int g2 = 0; g2 < 4; ++g2) {
                    int eb = base + g2 * 4;
                    int s0 = rfl(col[eb]), s1 = rfl(col[eb + 1]);
                    int s2 = rfl(col[eb + 2]), s3 = rfl(col[eb + 3]);
                    int c01 = (p & 1) ? s1 : s0;
                    int c23 = (p & 1) ? s3 : s2;
                    int c   = (p & 2) ? c23 : c01;
                    v[g2] = H4[(size_t)c * 16 + q];
                }
            };
            // tail batch: clamped indices (reads duplicate em; masked later)
            auto ISSUET = [&](uint4* v) {
#pragma unroll
                for (int g2 = 0; g2 < 4; ++g2) {
                    int eb = tb + g2 * 4;
                    int j0 = (eb     > em) ? em : eb;
                    int j1 = (eb + 1 > em) ? em : eb + 1;
                    int j2 = (eb + 2 > em) ? em : eb + 2;
                    int j3 = (eb + 3 > em) ? em : eb + 3;
                    int s0 = rfl(col[j0]), s1 = rfl(col[j1]);
                    int s2 = rfl(col[j2]), s3 = rfl(col[j3]);
                    int c01 = (p & 1) ? s1 : s0;
                    int c23 = (p & 1) ? s3 : s2;
                    int c   = (p & 2) ? c23 : c01;
                    v[g2] = H4[(size_t)c * 16 + q];
                }
            };
            auto CONSF = [&](const uint4* v) {
#pragma unroll
                for (int g2 = 0; g2 < 4; ++g2) {
                    acc2(a0, a1, v[g2].x); acc2(a2, a3, v[g2].y);
                    acc2(a4, a5, v[g2].z); acc2(a6, a7, v[g2].w);
                }
            };
            auto CONST_ = [&](const uint4* v) {
#pragma unroll
                for (int g2 = 0; g2 < 4; ++g2) {
                    uint4 u = v[g2];
                    if (tb + g2 * 4 + p >= e1) { u.x = 0u; u.y = 0u; u.z = 0u; u.w = 0u; }
                    acc2(a0, a1, u.x); acc2(a2, a3, u.y);
                    acc2(a4, a5, u.z); acc2(a6, a7, u.w);
                }
            };

            if (nfull > 0) {
                ISSUEF(va, e0);
                int b = 1;
#pragma unroll 1
                for (; b + 1 < nfull; b += 2) {    // steady: full batches only
                    ISSUEF(vb, e0 + 16 * b);
                    CONSF(va);
                    ISSUEF(va, e0 + 16 * (b + 1));
                    CONSF(vb);
                }
                if (b < nfull) {                   // vb is the last full batch
                    ISSUEF(vb, e0 + 16 * b);
                    CONSF(va);
                    if (tail) { ISSUET(va); CONSF(vb); CONST_(va); }
                    else      { CONSF(vb); }
                } else {                           // va holds the last full batch
                    if (tail) { ISSUET(vb); CONSF(va); CONST_(vb); }
                    else      { CONSF(va); }
                }
            } else {                               // deg < 16: one clamped batch
                ISSUET(va);
                CONST_(va);
            }
        }

        // sum the 4 edge slots
#pragma unroll
        for (int off = 16; off < 64; off <<= 1) {
            a0 += __shfl_xor(a0, off, 64); a1 += __shfl_xor(a1, off, 64);
            a2 += __shfl_xor(a2, off, 64); a3 += __shfl_xor(a3, off, 64);
            a4 += __shfl_xor(a4, off, 64); a5 += __shfl_xor(a5, off, 64);
            a6 += __shfl_xor(a6, off, 64); a7 += __shfl_xor(a7, off, 64);
        }
        if (p == 0) {
            uint4 pk;
            pk.x = pack_bf2(fmaxf(a0 * di, 0.f), fmaxf(a1 * di, 0.f));
            pk.y = pack_bf2(fmaxf(a2 * di, 0.f), fmaxf(a3 * di, 0.f));
            pk.z = pack_bf2(fmaxf(a4 * di, 0.f), fmaxf(a5 * di, 0.f));
            pk.w = pack_bf2(fmaxf(a6 * di, 0.f), fmaxf(a7 * di, 0.f));
            *(uint4*)&As[il * 128 + ((q ^ (il & 7)) << 3)] = pk;
        }
    }
    __syncthreads();

    // ---- phase 2: 32x64 = As(32x128) @ Ws^T
    const int rb = (w & 1) * 16;
    const int cb = (w >> 1) * 16;
    const int arow_l = rb + l15;
    const int asw = arow_l & 7;

    f32x4 acc;
    {
        float bv = b1[cb + l15];
        acc[0] = bv; acc[1] = bv; acc[2] = bv; acc[3] = bv;
    }
#pragma unroll
    for (int kc = 0; kc < 4; ++kc) {
        bf16x8 af = *(const bf16x8*)&As[arow_l * 128 + (((kc * 4 + quad) ^ asw) << 3)];
        int brow = cb + l15;
        bf16x8 bfr = *(const bf16x8*)&Ws[brow * 128 + (((kc * 4 + quad) ^ (brow & 7)) << 3)];
        acc = __builtin_amdgcn_mfma_f32_16x16x32_bf16(af, bfr, acc, 0, 0, 0);
    }

#pragma unroll
    for (int r4 = 0; r4 < 4; ++r4) {
        int grow = rbase + rb + quad * 4 + r4;
        float sc = deg_scale(row_ptr, grow);
        out[(size_t)grow * 64 + cb + l15] = __float2bfloat16(acc[r4] * sc);
    }
}

// ---------------------------------------------------------------------------
// SpMM (CSR, wave-per-row), F=64, fused log_softmax. Same discipline:
// full 8-edge batches ping-ponged with no masks; one clamped tail batch
// issued before the last full consume.
// ---------------------------------------------------------------------------
__global__ __launch_bounds__(256) void spmm_logsoftmax_64(const int* __restrict__ row_ptr,
                                                          const int* __restrict__ col,
                                                          const uint4* __restrict__ H4, // h2b rows = 8 uint4
                                                          float* __restrict__ out, int N) {
    const int lane = threadIdx.x & 63;
    const int p = lane >> 3;                  // edge slot 0..7
    const int q = lane & 7;                   // feature granule (8 features)
    int i = rfl(blockIdx.x * 4 + (threadIdx.x >> 6));
    if (i >= N) return;
    const int e0 = rfl(row_ptr[i]);
    const int e1 = rfl(row_ptr[i + 1]);
    const int dg = e1 - e0;
    const float di = (dg > 0) ? rsqrtf((float)dg) : 0.0f;
    float a0 = 0.f, a1 = 0.f, a2 = 0.f, a3 = 0.f,
          a4 = 0.f, a5 = 0.f, a6 = 0.f, a7 = 0.f;

    if (dg > 0) {
        const int em    = e1 - 1;
        const int nfull = dg >> 3;             // # full 8-edge batches
        const int tb    = e0 + (nfull << 3);   // tail base
        const bool tail = (dg & 7) != 0;
        uint4 ua, ub;

        auto PICK = [&](int s0, int s1, int s2, int s3,
                        int s4, int s5, int s6, int s7) {
            int b0 = (p & 1) ? s1 : s0, b1_ = (p & 1) ? s3 : s2;
            int b2 = (p & 1) ? s5 : s4, b3_ = (p & 1) ? s7 : s6;
            int c0 = (p & 2) ? b1_ : b0, c1 = (p & 2) ? b3_ : b2;
            return (p & 4) ? c1 : c0;
        };
        auto ISSUEF = [&](uint4& u, int base) {
            int c = PICK(rfl(col[base]),     rfl(col[base + 1]),
                         rfl(col[base + 2]), rfl(col[base + 3]),
                         rfl(col[base + 4]), rfl(col[base + 5]),
                         rfl(col[base + 6]), rfl(col[base + 7]));
            u = H4[(size_t)c * 8 + q];
        };
        auto ISSUET = [&](uint4& u) {
            int j0 = tb,     j1 = tb + 1, j2 = tb + 2, j3 = tb + 3;
            int j4 = tb + 4, j5 = tb + 5, j6 = tb + 6, j7 = tb + 7;
            j1 = (j1 > em) ? em : j1; j2 = (j2 > em) ? em : j2;
            j3 = (j3 > em) ? em : j3; j4 = (j4 > em) ? em : j4;
            j5 = (j5 > em) ? em : j5; j6 = (j6 > em) ? em : j6;
            j7 = (j7 > em) ? em : j7;
            int c = PICK(rfl(col[j0]), rfl(col[j1]), rfl(col[j2]), rfl(col[j3]),
                         rfl(col[j4]), rfl(col[j5]), rfl(col[j6]), rfl(col[j7]));
            u = H4[(size_t)c * 8 + q];
        };
        auto CONSF = [&](uint4 u) {
            acc2(a0, a1, u.x); acc2(a2, a3, u.y);
            acc2(a4, a5, u.z); acc2(a6, a7, u.w);
        };
        auto CONST_ = [&](uint4 u) {
            if (tb + p >= e1) { u.x = 0u; u.y = 0u; u.z = 0u; u.w = 0u; }
            acc2(a0, a1, u.x); acc2(a2, a3, u.y);
            acc2(a4, a5, u.z); acc2(a6, a7, u.w);
        };

        if (nfull > 0) {
            ISSUEF(ua, e0);
            int g = 1;
#pragma unroll 1
            for (; g + 1 < nfull; g += 2) {
                ISSUEF(ub, e0 + 8 * g);
                CONSF(ua);
                ISSUEF(ua, e0 + 8 * (g + 1));
                CONSF(ub);
            }
            if (g < nfull) {                   // ub is the last full batch
                ISSUEF(ub, e0 + 8 * g);
                CONSF(ua);
                if (tail) { ISSUET(ua); CONSF(ub); CONST_(ua); }
                else      { CONSF(ub); }
            } else {                           // ua holds the last full batch
                if (tail) { ISSUET(ub); CONSF(ua); CONST_(ub); }
                else      { CONSF(ua); }
            }
        } else {                               // deg < 8: one clamped batch
            ISSUET(ua);
            CONST_(ua);
        }
    }

    // sum the 8 edge slots
#pragma unroll
    for (int off = 8; off < 64; off <<= 1) {
        a0 += __shfl_xor(a0, off, 64); a1 += __shfl_xor(a1, off, 64);
        a2 += __shfl_xor(a2, off, 64); a3 += __shfl_xor(a3, off, 64);
        a4 += __shfl_xor(a4, off, 64); a5 += __shfl_xor(a5, off, 64);
        a6 += __shfl_xor(a6, off, 64); a7 += __shfl_xor(a7, off, 64);
    }
    a0 *= di; a1 *= di; a2 *= di; a3 *= di;
    a4 *= di; a5 *= di; a6 *= di; a7 *= di;
    // log_softmax over 64 features (8 per lane x 8 granules)
    float m = fmaxf(fmaxf(fmaxf(a0, a1), fmaxf(a2, a3)),
                    fmaxf(fmaxf(a4, a5), fmaxf(a6, a7)));
#pragma unroll
    for (int off = 1; off < 8; off <<= 1)
        m = fmaxf(m, __shfl_xor(m, off, 64));
    float s = __expf(a0 - m) + __expf(a1 - m) + __expf(a2 - m) + __expf(a3 - m)
            + __expf(a4 - m) + __expf(a5 - m) + __expf(a6 - m) + __expf(a7 - m);
#pragma unroll
    for (int off = 1; off < 8; off <<= 1)
        s += __shfl_xor(s, off, 64);
    float ls = __logf(s);
    if (p == 0) {
        float4 o0 = make_float4(a0 - m - ls, a1 - m - ls, a2 - m - ls, a3 - m - ls);
        float4 o1 = make_float4(a4 - m - ls, a5 - m - ls, a6 - m - ls, a7 - m - ls);
        *(float4*)&out[(size_t)i * 64 + q * 8]     = o0;
        *(float4*)&out[(size_t)i * 64 + q * 8 + 4] = o1;
    }
}

// ---------------------------------------------------------------------------
extern "C" void kernel_launch(void* const* d_in, const int* in_sizes, int n_in,
                              void* d_out, int out_size, void* d_ws, size_t ws_size,
                              hipStream_t stream) {
    const float* x    = (const float*)d_in[0];
    const int*   erow = (const int*)d_in[1];
    const int*   ecol = (const int*)d_in[2];
    const float* W0   = (const float*)d_in[3];
    const float* b0   = (const float*)d_in[4];
    const float* W1   = (const float*)d_in[5];
    const float* b1   = (const float*)d_in[6];
    float* out = (float*)d_out;

    char* ws = (char*)d_ws;
    // layout (bytes):
    //   [0, 512K)            row_ptr (100001 int)
    //   [1M, +25.6M)         h0b  bf16 100000*128   (pre-scaled by dinv[row])
    //   [27M, +12.8M)        h2b  bf16 100000*64    (pre-scaled by dinv[row])
    //   [41M, +32K)          Wt0  bf16 128*128 (as [n][k])
    //   [41.1M, +16K)        Wt1  bf16 64*128  (as [n][k])
    int*             row_ptr = (int*)ws;
    __hip_bfloat16*  h0b     = (__hip_bfloat16*)(ws + (1u << 20));
    __hip_bfloat16*  h2b     = (__hip_bfloat16*)(ws + 27000000u);
    __hip_bfloat16*  Wt0     = (__hip_bfloat16*)(ws + 41000000u);
    __hip_bfloat16*  Wt1     = (__hip_bfloat16*)(ws + 41100000u);

    // 1. prep: row_ptr + packed weights
    prep_kernel<<<NE / 256 + 96, 256, 0, stream>>>(erow, row_ptr, W0, W1, Wt0, Wt1);
    // 2. h0b = bf16(dinv[r] * (x @ W0 + b0))        [MFMA, shared-LDS]
    gemm_mfma<128, float><<<(NN + 127) / 128, 512, 0, stream>>>(x, Wt0, b0, row_ptr, h0b, NN);
    // 3. h2b = bf16(dinv[r] * (relu(spmm(h0b)) @ W1 + b1))   [full/tail pipelined]
    spmm_relu_gemm1<<<NN / 32, 512, 0, stream>>>(row_ptr, ecol,
                                                 (const uint4*)h0b, Wt1, b1, h2b);
    // 4. out = log_softmax(di * sum H[col])                  [full/tail pipelined]
    spmm_logsoftmax_64<<<(NN + 3) / 4, 256, 0, stream>>>(row_ptr, ecol,
                                                         (const uint4*)h2b, out, NN);
}